// Round 1
// baseline (851.666 us; speedup 1.0000x reference)
//
#include <hip/hip_runtime.h>

#define FDIM 64

// ---- detect whether edge_index is int64 (high dwords all zero) or int32 ----
__global__ void detect_dtype_kernel(const int* ei, int nsamp, int* flag) {
    __shared__ int any_nz;
    if (threadIdx.x == 0) any_nz = 0;
    __syncthreads();
    int local = 0;
    for (int i = threadIdx.x; i < nsamp; i += blockDim.x) {
        if (ei[2 * i + 1] != 0) local = 1;   // odd dword: int64 high word (==0) vs real int32 index
    }
    if (local) atomicOr(&any_nz, 1);
    __syncthreads();
    if (threadIdx.x == 0) flag[0] = (any_nz == 0) ? 1 : 0;   // 1 => int64
}

__global__ void convert_edges(const void* ei, const int* flag, int E, int* src, int* dst) {
    int is64 = flag[0];
    int i = blockIdx.x * blockDim.x + threadIdx.x;
    int stride = gridDim.x * blockDim.x;
    if (is64) {
        const long long* p = (const long long*)ei;
        for (; i < E; i += stride) { src[i] = (int)p[i]; dst[i] = (int)p[E + i]; }
    } else {
        const int* p = (const int*)ei;
        for (; i < E; i += stride) { src[i] = p[i]; dst[i] = p[E + i]; }
    }
}

__global__ void count_deg(const int* __restrict__ dst, int E, int* __restrict__ deg) {
    int i = blockIdx.x * blockDim.x + threadIdx.x;
    int stride = gridDim.x * blockDim.x;
    for (; i < E; i += stride) atomicAdd(&deg[dst[i]], 1);
}

__global__ void compute_dinv(const int* __restrict__ deg, int N, float* __restrict__ dinv) {
    int n = blockIdx.x * blockDim.x + threadIdx.x;
    if (n < N) {
        float d = (float)(deg[n] + 1);   // +1 for the self loop
        dinv[n] = rsqrtf(d);
    }
}

// y[n,:] = (x[n,:] @ W) * dinv[n]   — wave per 4 nodes, lane = out-feature
__global__ __launch_bounds__(256) void gemm_scale(const float* __restrict__ x,
                                                  const float* __restrict__ W,
                                                  const float* __restrict__ dinv,
                                                  float* __restrict__ y, int N) {
    __shared__ float Wl[FDIM * FDIM];
    for (int i = threadIdx.x; i < FDIM * FDIM; i += blockDim.x) Wl[i] = W[i];
    __syncthreads();
    int lane = threadIdx.x & 63;
    int gw = (blockIdx.x * blockDim.x + threadIdx.x) >> 6;
    int nw = (gridDim.x * blockDim.x) >> 6;
    for (int base = gw * 4; base < N; base += nw * 4) {
        int nvalid = min(4, N - base);
        float xv[4];
        float a[4] = {0.f, 0.f, 0.f, 0.f};
        #pragma unroll
        for (int i = 0; i < 4; i++)
            xv[i] = (i < nvalid) ? x[(base + i) * FDIM + lane] : 0.f;
        #pragma unroll
        for (int k = 0; k < FDIM; k++) {
            float wk = Wl[k * FDIM + lane];
            a[0] += __shfl(xv[0], k) * wk;
            a[1] += __shfl(xv[1], k) * wk;
            a[2] += __shfl(xv[2], k) * wk;
            a[3] += __shfl(xv[3], k) * wk;
        }
        #pragma unroll
        for (int i = 0; i < 4; i++)
            if (i < nvalid) y[(base + i) * FDIM + lane] = a[i] * dinv[base + i];
    }
}

// acc[dst,:] += y[src,:]   — wave per edge, lane = feature
__global__ void scatter_add(const int* __restrict__ src, const int* __restrict__ dst,
                            const float* __restrict__ y, float* __restrict__ acc, int E) {
    int lane = threadIdx.x & 63;
    int gw = (blockIdx.x * blockDim.x + threadIdx.x) >> 6;
    int nw = (gridDim.x * blockDim.x) >> 6;
    for (int e = gw; e < E; e += nw) {
        int s = src[e];
        int d = dst[e];
        float v = y[s * FDIM + lane];
        atomicAdd(&acc[d * FDIM + lane], v);
    }
}

// out[n,:] = dinv[n]*(acc[n,:] + y[n,:]) + b[:]   (self-loop folded in), optional ReLU
template <bool RELU>
__global__ void finalize_kernel(const float* __restrict__ acc, const float* __restrict__ y,
                                const float* __restrict__ dinv, const float* __restrict__ b,
                                float* __restrict__ out, int N) {
    int idx = blockIdx.x * blockDim.x + threadIdx.x;
    int stride = gridDim.x * blockDim.x;
    int total = N * (FDIM / 4);   // float4 units
    for (; idx < total; idx += stride) {
        int n = idx >> 4;
        int q = idx & 15;
        float4 a = ((const float4*)acc)[idx];
        float4 yy = ((const float4*)y)[idx];
        float4 bb = ((const float4*)b)[q];
        float dv = dinv[n];
        float4 o;
        o.x = dv * (a.x + yy.x) + bb.x;
        o.y = dv * (a.y + yy.y) + bb.y;
        o.z = dv * (a.z + yy.z) + bb.z;
        o.w = dv * (a.w + yy.w) + bb.w;
        if (RELU) {
            o.x = fmaxf(o.x, 0.f); o.y = fmaxf(o.y, 0.f);
            o.z = fmaxf(o.z, 0.f); o.w = fmaxf(o.w, 0.f);
        }
        ((float4*)out)[idx] = o;
    }
}

extern "C" void kernel_launch(void* const* d_in, const int* in_sizes, int n_in,
                              void* d_out, int out_size, void* d_ws, size_t ws_size,
                              hipStream_t stream) {
    const float* x  = (const float*)d_in[0];
    const void*  ei = d_in[1];
    const float* W1 = (const float*)d_in[2];
    const float* b1 = (const float*)d_in[3];
    const float* W2 = (const float*)d_in[4];
    const float* b2 = (const float*)d_in[5];
    float* out = (float*)d_out;

    int N = out_size / FDIM;          // 100000
    int E = in_sizes[1] / 2;          // 1200000

    // ws layout (all 16B-aligned by construction)
    char* ws = (char*)d_ws;
    int* flag = (int*)ws;                       // 256 B slot
    int* srcb = (int*)(ws + 256);               // E ints
    int* dstb = srcb + E;                       // E ints
    int* deg  = dstb + E;                       // N ints
    float* dinv = (float*)(deg + N);            // N floats
    float* y    = dinv + N;                     // N*64 floats
    float* acc  = y + (size_t)N * FDIM;         // N*64 floats

    // ---- graph prep (shared by both layers) ----
    hipMemsetAsync(deg, 0, (size_t)N * sizeof(int), stream);
    detect_dtype_kernel<<<1, 256, 0, stream>>>((const int*)ei, 2048, flag);
    convert_edges<<<2048, 256, 0, stream>>>(ei, flag, E, srcb, dstb);
    count_deg<<<2048, 256, 0, stream>>>(dstb, E, deg);
    compute_dinv<<<(N + 255) / 256, 256, 0, stream>>>(deg, N, dinv);

    // ---- layer 1: h = relu(GCNConv(x, W1, b1)) -> stored in d_out ----
    gemm_scale<<<1024, 256, 0, stream>>>(x, W1, dinv, y, N);
    hipMemsetAsync(acc, 0, (size_t)N * FDIM * sizeof(float), stream);
    scatter_add<<<2048, 256, 0, stream>>>(srcb, dstb, y, acc, E);
    finalize_kernel<true><<<2048, 256, 0, stream>>>(acc, y, dinv, b1, out, N);

    // ---- layer 2: out = GCNConv(h, W2, b2) ----
    gemm_scale<<<1024, 256, 0, stream>>>(out, W2, dinv, y, N);
    hipMemsetAsync(acc, 0, (size_t)N * FDIM * sizeof(float), stream);
    scatter_add<<<2048, 256, 0, stream>>>(srcb, dstb, y, acc, E);
    finalize_kernel<false><<<2048, 256, 0, stream>>>(acc, y, dinv, b2, out, N);
}

// Round 2
// 385.569 us; speedup vs baseline: 2.2089x; 2.2089x over previous
//
#include <hip/hip_runtime.h>

#define FDIM 64

// ---- detect whether edge_index is int64 (high dwords all zero) or int32 ----
__global__ void detect_dtype_kernel(const int* ei, int nsamp, int* flag) {
    __shared__ int any_nz;
    if (threadIdx.x == 0) any_nz = 0;
    __syncthreads();
    int local = 0;
    for (int i = threadIdx.x; i < nsamp; i += blockDim.x) {
        if (ei[2 * i + 1] != 0) local = 1;   // odd dword: int64 high word (==0) vs real int32 index
    }
    if (local) atomicOr(&any_nz, 1);
    __syncthreads();
    if (threadIdx.x == 0) flag[0] = (any_nz == 0) ? 1 : 0;   // 1 => int64
}

__global__ void convert_edges(const void* ei, const int* flag, int E, int* src, int* dst) {
    int is64 = flag[0];
    int i = blockIdx.x * blockDim.x + threadIdx.x;
    int stride = gridDim.x * blockDim.x;
    if (is64) {
        const long long* p = (const long long*)ei;
        for (; i < E; i += stride) { src[i] = (int)p[i]; dst[i] = (int)p[E + i]; }
    } else {
        const int* p = (const int*)ei;
        for (; i < E; i += stride) { src[i] = p[i]; dst[i] = p[E + i]; }
    }
}

__global__ void count_deg(const int* __restrict__ dst, int E, int* __restrict__ deg) {
    int i = blockIdx.x * blockDim.x + threadIdx.x;
    int stride = gridDim.x * blockDim.x;
    for (; i < E; i += stride) atomicAdd(&deg[dst[i]], 1);
}

__global__ void compute_dinv(const int* __restrict__ deg, int N, float* __restrict__ dinv) {
    int n = blockIdx.x * blockDim.x + threadIdx.x;
    if (n < N) {
        float d = (float)(deg[n] + 1);   // +1 for the self loop
        dinv[n] = rsqrtf(d);
    }
}

// ---- exclusive scan of deg[N] -> rowptr[N+1], 1024 elems per block ----
__global__ void scan1(const int* __restrict__ deg, int N, int* __restrict__ bsum) {
    __shared__ int lsum[256];
    int t = threadIdx.x;
    int base = blockIdx.x * 1024 + t * 4;
    int s = 0;
    #pragma unroll
    for (int i = 0; i < 4; i++) { int g = base + i; s += (g < N) ? deg[g] : 0; }
    lsum[t] = s; __syncthreads();
    for (int off = 128; off > 0; off >>= 1) {
        if (t < off) lsum[t] += lsum[t + off];
        __syncthreads();
    }
    if (t == 0) bsum[blockIdx.x] = lsum[0];
}

__global__ void scan2(int* bsum, int nb, int* rowptr, int N) {
    if (threadIdx.x == 0 && blockIdx.x == 0) {
        int run = 0;
        for (int i = 0; i < nb; i++) { int v = bsum[i]; bsum[i] = run; run += v; }
        rowptr[N] = run;
    }
}

__global__ void scan3(const int* __restrict__ deg, int N, const int* __restrict__ boff,
                      int* __restrict__ rowptr) {
    __shared__ int A[256], B[256];
    int t = threadIdx.x;
    int base = blockIdx.x * 1024 + t * 4;
    int v[4]; int s = 0;
    #pragma unroll
    for (int i = 0; i < 4; i++) { int g = base + i; v[i] = (g < N) ? deg[g] : 0; s += v[i]; }
    A[t] = s; __syncthreads();
    int* in = A; int* out = B;
    for (int off = 1; off < 256; off <<= 1) {
        out[t] = in[t] + ((t >= off) ? in[t - off] : 0);
        __syncthreads();
        int* tmp = in; in = out; out = tmp;
    }
    int excl = (t == 0) ? 0 : in[t - 1];
    int run = boff[blockIdx.x] + excl;
    #pragma unroll
    for (int i = 0; i < 4; i++) { int g = base + i; if (g < N) rowptr[g] = run; run += v[i]; }
}

// ---- bucket edges by dst: csr[rowptr[d] .. rowptr[d+1]) = src indices ----
__global__ void place_edges(const int* __restrict__ src, const int* __restrict__ dst, int E,
                            const int* __restrict__ rowptr, int* __restrict__ cursor,
                            int* __restrict__ csr) {
    int i = blockIdx.x * blockDim.x + threadIdx.x;
    int stride = gridDim.x * blockDim.x;
    for (; i < E; i += stride) {
        int d = dst[i];
        int pos = rowptr[d] + atomicAdd(&cursor[d], 1);
        csr[pos] = src[i];
    }
}

// ---- y[n,:] = (x[n,:] @ W) * dinv[n] — LDS-tiled, 64 nodes x 64 feats per block ----
__global__ __launch_bounds__(256) void gemm_scale(const float* __restrict__ x,
                                                  const float* __restrict__ W,
                                                  const float* __restrict__ dinv,
                                                  float* __restrict__ y, int N) {
    __shared__ float Xl[64 * 68];   // pad 68 so 4 rows at same k hit distinct banks
    __shared__ float Wl[64 * 64];
    int t = threadIdx.x;
    int nbase = blockIdx.x * 64;
    // stage W (4096 floats)
    for (int i = t; i < 1024; i += 256) {
        ((float4*)Wl)[i] = ((const float4*)W)[i];
    }
    // stage X tile (guarded)
    for (int i = t; i < 1024; i += 256) {
        int flat = i * 4;
        int n = flat >> 6, k = flat & 63;
        int g = nbase + n;
        float4 v = (g < N) ? *(const float4*)(x + (size_t)g * FDIM + k)
                           : make_float4(0.f, 0.f, 0.f, 0.f);
        *(float4*)&Xl[n * 68 + k] = v;
    }
    __syncthreads();

    int fr = t & 15;    // feature group: feats fr*4..fr*4+3
    int ng = t >> 4;    // node group:    nodes ng*4..ng*4+3
    float acc[4][4] = {{0.f}};
    #pragma unroll
    for (int kc = 0; kc < 16; kc++) {
        float4 xa[4], wa[4];
        #pragma unroll
        for (int i = 0; i < 4; i++) xa[i] = *(float4*)&Xl[(ng * 4 + i) * 68 + kc * 4];
        #pragma unroll
        for (int j = 0; j < 4; j++) wa[j] = *(float4*)&Wl[(kc * 4 + j) * 64 + fr * 4];
        #pragma unroll
        for (int i = 0; i < 4; i++) {
            acc[i][0] += xa[i].x * wa[0].x + xa[i].y * wa[1].x + xa[i].z * wa[2].x + xa[i].w * wa[3].x;
            acc[i][1] += xa[i].x * wa[0].y + xa[i].y * wa[1].y + xa[i].z * wa[2].y + xa[i].w * wa[3].y;
            acc[i][2] += xa[i].x * wa[0].z + xa[i].y * wa[1].z + xa[i].z * wa[2].z + xa[i].w * wa[3].z;
            acc[i][3] += xa[i].x * wa[0].w + xa[i].y * wa[1].w + xa[i].z * wa[2].w + xa[i].w * wa[3].w;
        }
    }
    #pragma unroll
    for (int i = 0; i < 4; i++) {
        int g = nbase + ng * 4 + i;
        if (g < N) {
            float dv = dinv[g];
            float4 o = make_float4(acc[i][0] * dv, acc[i][1] * dv, acc[i][2] * dv, acc[i][3] * dv);
            *(float4*)(y + (size_t)g * FDIM + fr * 4) = o;
        }
    }
}

// ---- out[n,:] = dinv[n]*(y[n,:] + sum_{e in bucket(n)} y[src_e,:]) + b  (+ReLU) ----
template <bool RELU>
__global__ __launch_bounds__(256) void gather(const int* __restrict__ rowptr,
                                              const int* __restrict__ csr,
                                              const float* __restrict__ y,
                                              const float* __restrict__ dinv,
                                              const float* __restrict__ b,
                                              float* __restrict__ out, int N) {
    int lane = threadIdx.x & 63;
    int n = blockIdx.x * 4 + (threadIdx.x >> 6);
    if (n >= N) return;
    int start = rowptr[n], end = rowptr[n + 1];
    float acc = y[(size_t)n * FDIM + lane];   // self loop (pre-scaled by dinv[n])
    for (int base = start; base < end; base += 64) {
        int m = end - base; if (m > 64) m = 64;
        int idx = (lane < m) ? csr[base + lane] : 0;
        int j = 0;
        for (; j + 1 < m; j += 2) {
            int s0 = __shfl(idx, j);
            int s1 = __shfl(idx, j + 1);
            float v0 = y[(size_t)s0 * FDIM + lane];
            float v1 = y[(size_t)s1 * FDIM + lane];
            acc += v0;
            acc += v1;
        }
        if (j < m) {
            int s0 = __shfl(idx, j);
            acc += y[(size_t)s0 * FDIM + lane];
        }
    }
    float o = acc * dinv[n] + b[lane];
    if (RELU) o = fmaxf(o, 0.f);
    out[(size_t)n * FDIM + lane] = o;
}

extern "C" void kernel_launch(void* const* d_in, const int* in_sizes, int n_in,
                              void* d_out, int out_size, void* d_ws, size_t ws_size,
                              hipStream_t stream) {
    const float* x  = (const float*)d_in[0];
    const void*  ei = d_in[1];
    const float* W1 = (const float*)d_in[2];
    const float* b1 = (const float*)d_in[3];
    const float* W2 = (const float*)d_in[4];
    const float* b2 = (const float*)d_in[5];
    float* out = (float*)d_out;

    int N = out_size / FDIM;          // 100000
    int E = in_sizes[1] / 2;          // 1200000
    int NB = (N + 1023) / 1024;       // scan blocks

    // ws layout — float4-accessed buffers first (16B aligned at ws+0)
    float* y    = (float*)d_ws;               // N*64
    float* dinv = y + (size_t)N * FDIM;       // N
    int* flag   = (int*)(dinv + N);           // 64
    int* srcb   = flag + 64;                  // E
    int* dstb   = srcb + E;                   // E
    int* deg    = dstb + E;                   // N
    int* rowptr = deg + N;                    // N+1
    int* cursor = rowptr + N + 1;             // N
    int* bsum   = cursor + N;                 // 256
    int* csr    = bsum + 256;                 // E

    // ---- graph prep (shared by both layers) ----
    hipMemsetAsync(deg, 0, (size_t)N * sizeof(int), stream);
    hipMemsetAsync(cursor, 0, (size_t)N * sizeof(int), stream);
    detect_dtype_kernel<<<1, 256, 0, stream>>>((const int*)ei, 2048, flag);
    convert_edges<<<2048, 256, 0, stream>>>(ei, flag, E, srcb, dstb);
    count_deg<<<2048, 256, 0, stream>>>(dstb, E, deg);
    compute_dinv<<<(N + 255) / 256, 256, 0, stream>>>(deg, N, dinv);
    scan1<<<NB, 256, 0, stream>>>(deg, N, bsum);
    scan2<<<1, 64, 0, stream>>>(bsum, NB, rowptr, N);
    scan3<<<NB, 256, 0, stream>>>(deg, N, bsum, rowptr);
    place_edges<<<2048, 256, 0, stream>>>(srcb, dstb, E, rowptr, cursor, csr);

    int gemm_grid = (N + 63) / 64;
    int gath_grid = (N + 3) / 4;

    // ---- layer 1: h = relu(GCNConv(x, W1, b1)) -> d_out ----
    gemm_scale<<<gemm_grid, 256, 0, stream>>>(x, W1, dinv, y, N);
    gather<true><<<gath_grid, 256, 0, stream>>>(rowptr, csr, y, dinv, b1, out, N);

    // ---- layer 2: out = GCNConv(h, W2, b2) ----
    gemm_scale<<<gemm_grid, 256, 0, stream>>>(out, W2, dinv, y, N);
    gather<false><<<gath_grid, 256, 0, stream>>>(rowptr, csr, y, dinv, b2, out, N);
}

// Round 3
// 332.839 us; speedup vs baseline: 2.5588x; 1.1584x over previous
//
#include <hip/hip_runtime.h>

#define FDIM 64

// ---- detect whether edge_index is int64 (high dwords all zero) or int32 ----
__global__ void detect_dtype_kernel(const int* ei, int nsamp, int* flag) {
    __shared__ int any_nz;
    if (threadIdx.x == 0) any_nz = 0;
    __syncthreads();
    int local = 0;
    for (int i = threadIdx.x; i < nsamp; i += blockDim.x) {
        if (ei[2 * i + 1] != 0) local = 1;   // odd dword: int64 high word (==0) vs real int32 index
    }
    if (local) atomicOr(&any_nz, 1);
    __syncthreads();
    if (threadIdx.x == 0) flag[0] = (any_nz == 0) ? 1 : 0;   // 1 => int64
}

__global__ void convert_edges(const void* ei, const int* flag, int E, int* src, int* dst) {
    int is64 = flag[0];
    int i = blockIdx.x * blockDim.x + threadIdx.x;
    int stride = gridDim.x * blockDim.x;
    if (is64) {
        const long long* p = (const long long*)ei;
        for (; i < E; i += stride) { src[i] = (int)p[i]; dst[i] = (int)p[E + i]; }
    } else {
        const int* p = (const int*)ei;
        for (; i < E; i += stride) { src[i] = p[i]; dst[i] = p[E + i]; }
    }
}

__global__ void count_deg(const int* __restrict__ dst, int E, int* __restrict__ deg) {
    int i = blockIdx.x * blockDim.x + threadIdx.x;
    int stride = gridDim.x * blockDim.x;
    for (; i < E; i += stride) atomicAdd(&deg[dst[i]], 1);
}

__global__ void compute_dinv(const int* __restrict__ deg, int N, float* __restrict__ dinv) {
    int n = blockIdx.x * blockDim.x + threadIdx.x;
    if (n < N) {
        float d = (float)(deg[n] + 1);   // +1 for the self loop
        dinv[n] = rsqrtf(d);
    }
}

// ---- exclusive scan of deg[N] -> rowptr[N+1], 1024 elems per block ----
__global__ void scan1(const int* __restrict__ deg, int N, int* __restrict__ bsum) {
    __shared__ int lsum[256];
    int t = threadIdx.x;
    int base = blockIdx.x * 1024 + t * 4;
    int s = 0;
    #pragma unroll
    for (int i = 0; i < 4; i++) { int g = base + i; s += (g < N) ? deg[g] : 0; }
    lsum[t] = s; __syncthreads();
    for (int off = 128; off > 0; off >>= 1) {
        if (t < off) lsum[t] += lsum[t + off];
        __syncthreads();
    }
    if (t == 0) bsum[blockIdx.x] = lsum[0];
}

__global__ void scan2(int* bsum, int nb, int* rowptr, int N) {
    if (threadIdx.x == 0 && blockIdx.x == 0) {
        int run = 0;
        for (int i = 0; i < nb; i++) { int v = bsum[i]; bsum[i] = run; run += v; }
        rowptr[N] = run;
    }
}

__global__ void scan3(const int* __restrict__ deg, int N, const int* __restrict__ boff,
                      int* __restrict__ rowptr) {
    __shared__ int A[256], B[256];
    int t = threadIdx.x;
    int base = blockIdx.x * 1024 + t * 4;
    int v[4]; int s = 0;
    #pragma unroll
    for (int i = 0; i < 4; i++) { int g = base + i; v[i] = (g < N) ? deg[g] : 0; s += v[i]; }
    A[t] = s; __syncthreads();
    int* in = A; int* out = B;
    for (int off = 1; off < 256; off <<= 1) {
        out[t] = in[t] + ((t >= off) ? in[t - off] : 0);
        __syncthreads();
        int* tmp = in; in = out; out = tmp;
    }
    int excl = (t == 0) ? 0 : in[t - 1];
    int run = boff[blockIdx.x] + excl;
    #pragma unroll
    for (int i = 0; i < 4; i++) { int g = base + i; if (g < N) rowptr[g] = run; run += v[i]; }
}

// ---- bucket edges by dst with XCD-affine csr writes ----
// Block-group g (= blockIdx&7, presumed XCD via round-robin dispatch) sweeps ALL
// edges, places only those whose node-bucket r=(dst>>12)&31 has (r&7)==g.
// Each XCD then writes a private ~1/8 slice of csr -> stays in its L2.
__global__ __launch_bounds__(256) void place_edges(const int* __restrict__ src,
                                                   const int* __restrict__ dst, int E,
                                                   const int* __restrict__ rowptr,
                                                   int* __restrict__ cursor,
                                                   int* __restrict__ csr) {
    int g = blockIdx.x & 7;
    int gblk = blockIdx.x >> 3;                 // block index within group
    int ngblk = gridDim.x >> 3;                 // blocks per group
    int gtid = gblk * blockDim.x + threadIdx.x; // thread index within group
    int gstride = ngblk * blockDim.x;
    for (int i = gtid; i < E; i += gstride) {
        int d = dst[i];
        int r = (d >> 12) & 31;
        if ((r & 7) == g) {
            int s = src[i];
            int pos = rowptr[d] + atomicAdd(&cursor[d], 1);
            csr[pos] = s;
        }
    }
}

// ---- y[n,:] = (x[n,:] @ W) * dinv[n] — 1 wave/block, W column in VGPRs,
//      x row via wave-uniform loads (scalar-load path), lane = out-feature ----
__global__ __launch_bounds__(64) void gemm_scale(const float* __restrict__ x,
                                                 const float* __restrict__ W,
                                                 const float* __restrict__ dinv,
                                                 float* __restrict__ y, int N) {
    int lane = threadIdx.x;   // 0..63
    float wcol[64];
    #pragma unroll
    for (int k = 0; k < 16; k++) {
        float4 wv = *(const float4*)(W + (4 * k + 0) * FDIM + 0);  // dummy to keep pattern simple
        (void)wv;
    }
    #pragma unroll
    for (int k = 0; k < 64; k++) wcol[k] = W[k * FDIM + lane];     // coalesced, L2-hot

    for (int n = blockIdx.x * 2; n < N; n += gridDim.x * 2) {
        const float* xr0 = x + (size_t)n * FDIM;
        float acc0 = 0.f, acc1 = 0.f;
        bool two = (n + 1) < N;
        const float* xr1 = two ? xr0 + FDIM : xr0;
        #pragma unroll
        for (int q = 0; q < 16; q++) {
            float4 a = ((const float4*)xr0)[q];   // uniform address -> s_load/broadcast
            float4 b = ((const float4*)xr1)[q];
            acc0 += a.x * wcol[4 * q] + a.y * wcol[4 * q + 1] + a.z * wcol[4 * q + 2] + a.w * wcol[4 * q + 3];
            acc1 += b.x * wcol[4 * q] + b.y * wcol[4 * q + 1] + b.z * wcol[4 * q + 2] + b.w * wcol[4 * q + 3];
        }
        y[(size_t)n * FDIM + lane] = acc0 * dinv[n];
        if (two) y[(size_t)(n + 1) * FDIM + lane] = acc1 * dinv[n + 1];
    }
}

// ---- out[n,:] = dinv[n]*(y[n,:] + sum_{e in bucket(n)} y[src_e,:]) + b  (+ReLU) ----
template <bool RELU>
__global__ __launch_bounds__(256) void gather(const int* __restrict__ rowptr,
                                              const int* __restrict__ csr,
                                              const float* __restrict__ y,
                                              const float* __restrict__ dinv,
                                              const float* __restrict__ b,
                                              float* __restrict__ out, int N) {
    int lane = threadIdx.x & 63;
    int n = blockIdx.x * 4 + (threadIdx.x >> 6);
    if (n >= N) return;
    int start = rowptr[n], end = rowptr[n + 1];
    float acc = y[(size_t)n * FDIM + lane];   // self loop (pre-scaled by dinv[n])
    for (int base = start; base < end; base += 64) {
        int m = end - base; if (m > 64) m = 64;
        int idx = (lane < m) ? csr[base + lane] : 0;
        int j = 0;
        for (; j + 1 < m; j += 2) {
            int s0 = __shfl(idx, j);
            int s1 = __shfl(idx, j + 1);
            float v0 = y[(size_t)s0 * FDIM + lane];
            float v1 = y[(size_t)s1 * FDIM + lane];
            acc += v0;
            acc += v1;
        }
        if (j < m) {
            int s0 = __shfl(idx, j);
            acc += y[(size_t)s0 * FDIM + lane];
        }
    }
    float o = acc * dinv[n] + b[lane];
    if (RELU) o = fmaxf(o, 0.f);
    out[(size_t)n * FDIM + lane] = o;
}

extern "C" void kernel_launch(void* const* d_in, const int* in_sizes, int n_in,
                              void* d_out, int out_size, void* d_ws, size_t ws_size,
                              hipStream_t stream) {
    const float* x  = (const float*)d_in[0];
    const void*  ei = d_in[1];
    const float* W1 = (const float*)d_in[2];
    const float* b1 = (const float*)d_in[3];
    const float* W2 = (const float*)d_in[4];
    const float* b2 = (const float*)d_in[5];
    float* out = (float*)d_out;

    int N = out_size / FDIM;          // 100000
    int E = in_sizes[1] / 2;          // 1200000
    int NB = (N + 1023) / 1024;       // scan blocks

    // ws layout — float4-accessed buffers first (16B aligned at ws+0)
    float* y    = (float*)d_ws;               // N*64
    float* dinv = y + (size_t)N * FDIM;       // N
    int* flag   = (int*)(dinv + N);           // 64
    int* srcb   = flag + 64;                  // E
    int* dstb   = srcb + E;                   // E
    int* deg    = dstb + E;                   // N
    int* rowptr = deg + N;                    // N+1
    int* cursor = rowptr + N + 1;             // N
    int* bsum   = cursor + N;                 // 256
    int* csr    = bsum + 256;                 // E

    // ---- graph prep (shared by both layers) ----
    hipMemsetAsync(deg, 0, (size_t)N * sizeof(int), stream);
    hipMemsetAsync(cursor, 0, (size_t)N * sizeof(int), stream);
    detect_dtype_kernel<<<1, 256, 0, stream>>>((const int*)ei, 2048, flag);
    convert_edges<<<2048, 256, 0, stream>>>(ei, flag, E, srcb, dstb);
    count_deg<<<2048, 256, 0, stream>>>(dstb, E, deg);
    compute_dinv<<<(N + 255) / 256, 256, 0, stream>>>(deg, N, dinv);
    scan1<<<NB, 256, 0, stream>>>(deg, N, bsum);
    scan2<<<1, 64, 0, stream>>>(bsum, NB, rowptr, N);
    scan3<<<NB, 256, 0, stream>>>(deg, N, bsum, rowptr);
    place_edges<<<2048, 256, 0, stream>>>(srcb, dstb, E, rowptr, cursor, csr);

    int gath_grid = (N + 3) / 4;

    // ---- layer 1: h = relu(GCNConv(x, W1, b1)) -> d_out ----
    gemm_scale<<<4096, 64, 0, stream>>>(x, W1, dinv, y, N);
    gather<true><<<gath_grid, 256, 0, stream>>>(rowptr, csr, y, dinv, b1, out, N);

    // ---- layer 2: out = GCNConv(h, W2, b2) ----
    gemm_scale<<<4096, 64, 0, stream>>>(out, W2, dinv, y, N);
    gather<false><<<gath_grid, 256, 0, stream>>>(rowptr, csr, y, dinv, b2, out, N);
}

// Round 4
// 287.321 us; speedup vs baseline: 2.9642x; 1.1584x over previous
//
#include <hip/hip_runtime.h>

#define FDIM 64

// ---- detect whether edge_index is int64 (high dwords all zero) or int32 ----
__global__ void detect_dtype_kernel(const int* ei, int nsamp, int* flag) {
    __shared__ int any_nz;
    if (threadIdx.x == 0) any_nz = 0;
    __syncthreads();
    int local = 0;
    for (int i = threadIdx.x; i < nsamp; i += blockDim.x) {
        if (ei[2 * i + 1] != 0) local = 1;   // odd dword: int64 high word (==0) vs real int32 index
    }
    if (local) atomicOr(&any_nz, 1);
    __syncthreads();
    if (threadIdx.x == 0) flag[0] = (any_nz == 0) ? 1 : 0;   // 1 => int64
}

// ---- convert to int32 + count in-degree in the same pass ----
__global__ void convert_edges(const void* ei, const int* flag, int E, int* src, int* dst,
                              int* __restrict__ deg) {
    int is64 = flag[0];
    int i = blockIdx.x * blockDim.x + threadIdx.x;
    int stride = gridDim.x * blockDim.x;
    if (is64) {
        const long long* p = (const long long*)ei;
        for (; i < E; i += stride) {
            int s = (int)p[i], d = (int)p[E + i];
            src[i] = s; dst[i] = d;
            atomicAdd(&deg[d], 1);
        }
    } else {
        const int* p = (const int*)ei;
        for (; i < E; i += stride) {
            int s = p[i], d = p[E + i];
            src[i] = s; dst[i] = d;
            atomicAdd(&deg[d], 1);
        }
    }
}

// ---- exclusive scan of deg[N] -> rowptr[N+1], 1024 elems per block ----
__global__ void scan1(const int* __restrict__ deg, int N, int* __restrict__ bsum) {
    __shared__ int lsum[256];
    int t = threadIdx.x;
    int base = blockIdx.x * 1024 + t * 4;
    int s = 0;
    #pragma unroll
    for (int i = 0; i < 4; i++) { int g = base + i; s += (g < N) ? deg[g] : 0; }
    lsum[t] = s; __syncthreads();
    for (int off = 128; off > 0; off >>= 1) {
        if (t < off) lsum[t] += lsum[t + off];
        __syncthreads();
    }
    if (t == 0) bsum[blockIdx.x] = lsum[0];
}

// parallel single-block exclusive scan of bsum[nb] (nb<=256 fast path)
__global__ void scan2(int* bsum, int nb, int* rowptr, int N) {
    __shared__ int A[256], B[256];
    int t = threadIdx.x;
    if (nb <= 256) {
        int v = (t < nb) ? bsum[t] : 0;
        A[t] = v; __syncthreads();
        int* in = A; int* out = B;
        for (int off = 1; off < 256; off <<= 1) {
            out[t] = in[t] + ((t >= off) ? in[t - off] : 0);
            __syncthreads();
            int* z = in; in = out; out = z;
        }
        if (t < nb) bsum[t] = in[t] - v;           // exclusive
        if (t == 0) rowptr[N] = in[255];            // total (padding adds 0)
    } else if (t == 0) {
        int run = 0;
        for (int i = 0; i < nb; i++) { int v = bsum[i]; bsum[i] = run; run += v; }
        rowptr[N] = run;
    }
}

// scan3 also emits dinv = rsqrt(deg+1)
__global__ void scan3(const int* __restrict__ deg, int N, const int* __restrict__ boff,
                      int* __restrict__ rowptr, float* __restrict__ dinv) {
    __shared__ int A[256], B[256];
    int t = threadIdx.x;
    int base = blockIdx.x * 1024 + t * 4;
    int v[4]; int s = 0;
    #pragma unroll
    for (int i = 0; i < 4; i++) { int g = base + i; v[i] = (g < N) ? deg[g] : 0; s += v[i]; }
    A[t] = s; __syncthreads();
    int* in = A; int* out = B;
    for (int off = 1; off < 256; off <<= 1) {
        out[t] = in[t] + ((t >= off) ? in[t - off] : 0);
        __syncthreads();
        int* tmp = in; in = out; out = tmp;
    }
    int excl = (t == 0) ? 0 : in[t - 1];
    int run = boff[blockIdx.x] + excl;
    #pragma unroll
    for (int i = 0; i < 4; i++) {
        int g = base + i;
        if (g < N) {
            rowptr[g] = run;
            dinv[g] = rsqrtf((float)(v[i] + 1));
        }
        run += v[i];
    }
}

// ---- bucket edges by dst with XCD-affine csr writes ----
__global__ __launch_bounds__(256) void place_edges(const int* __restrict__ src,
                                                   const int* __restrict__ dst, int E,
                                                   const int* __restrict__ rowptr,
                                                   int* __restrict__ cursor,
                                                   int* __restrict__ csr) {
    int g = blockIdx.x & 7;
    int gblk = blockIdx.x >> 3;
    int ngblk = gridDim.x >> 3;
    int gtid = gblk * blockDim.x + threadIdx.x;
    int gstride = ngblk * blockDim.x;
    for (int i = gtid; i < E; i += gstride) {
        int d = dst[i];
        int r = (d >> 12) & 31;
        if ((r & 7) == g) {
            int s = src[i];
            int pos = rowptr[d] + atomicAdd(&cursor[d], 1);
            csr[pos] = s;
        }
    }
}

// ---- y[n,:] = (x[n,:] @ W) * dinv[n] — LDS-tiled 64x64, bounded regs ----
__global__ __launch_bounds__(256, 4) void gemm_scale(const float* __restrict__ x,
                                                     const float* __restrict__ W,
                                                     const float* __restrict__ dinv,
                                                     float* __restrict__ y, int N) {
    __shared__ float Xl[64 * 68];   // pad to 68 to break bank aliasing
    __shared__ float Wl[64 * 64];
    int t = threadIdx.x;
    int nbase = blockIdx.x * 64;
    for (int i = t; i < 1024; i += 256) {
        ((float4*)Wl)[i] = ((const float4*)W)[i];
    }
    for (int i = t; i < 1024; i += 256) {
        int flat = i * 4;
        int n = flat >> 6, k = flat & 63;
        int g = nbase + n;
        float4 v = (g < N) ? *(const float4*)(x + (size_t)g * FDIM + k)
                           : make_float4(0.f, 0.f, 0.f, 0.f);
        *(float4*)&Xl[n * 68 + k] = v;
    }
    __syncthreads();

    int fr = t & 15;    // feature group: feats fr*4..fr*4+3
    int ng = t >> 4;    // node group:    nodes ng*4..ng*4+3
    float acc[4][4] = {{0.f}};
    #pragma unroll 4
    for (int kc = 0; kc < 16; kc++) {
        float4 xa[4], wa[4];
        #pragma unroll
        for (int i = 0; i < 4; i++) xa[i] = *(float4*)&Xl[(ng * 4 + i) * 68 + kc * 4];
        #pragma unroll
        for (int j = 0; j < 4; j++) wa[j] = *(float4*)&Wl[(kc * 4 + j) * 64 + fr * 4];
        #pragma unroll
        for (int i = 0; i < 4; i++) {
            acc[i][0] += xa[i].x * wa[0].x + xa[i].y * wa[1].x + xa[i].z * wa[2].x + xa[i].w * wa[3].x;
            acc[i][1] += xa[i].x * wa[0].y + xa[i].y * wa[1].y + xa[i].z * wa[2].y + xa[i].w * wa[3].y;
            acc[i][2] += xa[i].x * wa[0].z + xa[i].y * wa[1].z + xa[i].z * wa[2].z + xa[i].w * wa[3].z;
            acc[i][3] += xa[i].x * wa[0].w + xa[i].y * wa[1].w + xa[i].z * wa[2].w + xa[i].w * wa[3].w;
        }
    }
    #pragma unroll
    for (int i = 0; i < 4; i++) {
        int g = nbase + ng * 4 + i;
        if (g < N) {
            float dv = dinv[g];
            float4 o = make_float4(acc[i][0] * dv, acc[i][1] * dv, acc[i][2] * dv, acc[i][3] * dv);
            *(float4*)(y + (size_t)g * FDIM + fr * 4) = o;
        }
    }
}

// ---- out[n,:] = dinv[n]*(y[n,:] + sum_{e in bucket(n)} y[src_e,:]) + b  (+ReLU) ----
template <bool RELU>
__global__ __launch_bounds__(256) void gather(const int* __restrict__ rowptr,
                                              const int* __restrict__ csr,
                                              const float* __restrict__ y,
                                              const float* __restrict__ dinv,
                                              const float* __restrict__ b,
                                              float* __restrict__ out, int N) {
    int lane = threadIdx.x & 63;
    int n = blockIdx.x * 4 + (threadIdx.x >> 6);
    if (n >= N) return;
    int start = rowptr[n], end = rowptr[n + 1];
    float acc = y[(size_t)n * FDIM + lane];   // self loop (pre-scaled by dinv[n])
    for (int base = start; base < end; base += 64) {
        int m = end - base; if (m > 64) m = 64;
        int idx = (lane < m) ? csr[base + lane] : 0;
        int j = 0;
        for (; j + 3 < m; j += 4) {
            int s0 = __shfl(idx, j);
            int s1 = __shfl(idx, j + 1);
            int s2 = __shfl(idx, j + 2);
            int s3 = __shfl(idx, j + 3);
            float v0 = y[(size_t)s0 * FDIM + lane];
            float v1 = y[(size_t)s1 * FDIM + lane];
            float v2 = y[(size_t)s2 * FDIM + lane];
            float v3 = y[(size_t)s3 * FDIM + lane];
            acc += v0; acc += v1; acc += v2; acc += v3;
        }
        for (; j < m; j++) {
            int s0 = __shfl(idx, j);
            acc += y[(size_t)s0 * FDIM + lane];
        }
    }
    float o = acc * dinv[n] + b[lane];
    if (RELU) o = fmaxf(o, 0.f);
    out[(size_t)n * FDIM + lane] = o;
}

extern "C" void kernel_launch(void* const* d_in, const int* in_sizes, int n_in,
                              void* d_out, int out_size, void* d_ws, size_t ws_size,
                              hipStream_t stream) {
    const float* x  = (const float*)d_in[0];
    const void*  ei = d_in[1];
    const float* W1 = (const float*)d_in[2];
    const float* b1 = (const float*)d_in[3];
    const float* W2 = (const float*)d_in[4];
    const float* b2 = (const float*)d_in[5];
    float* out = (float*)d_out;

    int N = out_size / FDIM;          // 100000
    int E = in_sizes[1] / 2;          // 1200000
    int NB = (N + 1023) / 1024;       // scan blocks (98)

    // ws layout — float4-accessed buffers first (16B aligned at ws+0)
    float* y    = (float*)d_ws;               // N*64
    float* dinv = y + (size_t)N * FDIM;       // N
    int* flag   = (int*)(dinv + N);           // 64
    int* srcb   = flag + 64;                  // E
    int* dstb   = srcb + E;                   // E
    int* deg    = dstb + E;                   // N
    int* rowptr = deg + N;                    // N+1
    int* cursor = rowptr + N + 1;             // N
    int* bsum   = cursor + N;                 // 256
    int* csr    = bsum + 256;                 // E

    // ---- graph prep (shared by both layers) ----
    hipMemsetAsync(deg, 0, (size_t)N * sizeof(int), stream);
    hipMemsetAsync(cursor, 0, (size_t)N * sizeof(int), stream);
    detect_dtype_kernel<<<1, 256, 0, stream>>>((const int*)ei, 2048, flag);
    convert_edges<<<2048, 256, 0, stream>>>(ei, flag, E, srcb, dstb, deg);
    scan1<<<NB, 256, 0, stream>>>(deg, N, bsum);
    scan2<<<1, 256, 0, stream>>>(bsum, NB, rowptr, N);
    scan3<<<NB, 256, 0, stream>>>(deg, N, bsum, rowptr, dinv);
    place_edges<<<2048, 256, 0, stream>>>(srcb, dstb, E, rowptr, cursor, csr);

    int gemm_grid = (N + 63) / 64;
    int gath_grid = (N + 3) / 4;

    // ---- layer 1: h = relu(GCNConv(x, W1, b1)) -> d_out ----
    gemm_scale<<<gemm_grid, 256, 0, stream>>>(x, W1, dinv, y, N);
    gather<true><<<gath_grid, 256, 0, stream>>>(rowptr, csr, y, dinv, b1, out, N);

    // ---- layer 2: out = GCNConv(h, W2, b2) ----
    gemm_scale<<<gemm_grid, 256, 0, stream>>>(out, W2, dinv, y, N);
    gather<false><<<gath_grid, 256, 0, stream>>>(rowptr, csr, y, dinv, b2, out, N);
}